// Round 1
// 138.657 us; speedup vs baseline: 1.0430x; 1.0430x over previous
//
#include <hip/hip_runtime.h>

using half2v  = __attribute__((ext_vector_type(2))) _Float16;
using half4   = __attribute__((ext_vector_type(4))) _Float16;
using half8   = __attribute__((ext_vector_type(8))) _Float16;
using floatx4 = __attribute__((ext_vector_type(4))) float;

constexpr int BATCH = 2;
constexpr int NPOS  = 96 * 96;    // 9216
constexpr int NT    = NPOS / 16;  // 576 sixteen-wide i-tiles
constexpr int NST   = NPOS / 32;  // 288 thirty-two-wide j-steps

#define EXP2(x) __builtin_amdgcn_exp2f(x)
#define MFMA16(A, B, C) __builtin_amdgcn_mfma_f32_16x16x16f16(A, B, C, 0, 0, 0)
#define MFMA32(A, B, C) __builtin_amdgcn_mfma_f32_16x16x32_f16(A, B, C, 0, 0, 0)

__device__ inline half8 p8_of(floatx4 e0, floatx4 e1) {
    half2v a0 = __builtin_bit_cast(half2v,
        __builtin_amdgcn_cvt_pkrtz(EXP2(e0[0]), EXP2(e0[1])));
    half2v a1 = __builtin_bit_cast(half2v,
        __builtin_amdgcn_cvt_pkrtz(EXP2(e0[2]), EXP2(e0[3])));
    half2v a2 = __builtin_bit_cast(half2v,
        __builtin_amdgcn_cvt_pkrtz(EXP2(e1[0]), EXP2(e1[1])));
    half2v a3 = __builtin_bit_cast(half2v,
        __builtin_amdgcn_cvt_pkrtz(EXP2(e1[2]), EXP2(e1[3])));
    half8 p = {a0[0], a0[1], a1[0], a1[1], a2[0], a2[1], a3[0], a3[1]};
    return p;
}

// ---------------------------------------------------------------------------
// K1: QKV projection (unchanged this round).
// Qf: j-permuted A-layout, log2e-scaled, d>=8 zeroed (denom runs pre-patch).
// Kf: B-layout, d=8,9 = 1.0 (augment channels). Vf: K=32 A-layout f16.
// ---------------------------------------------------------------------------
__global__ __launch_bounds__(256) void qkv_kernel(
    const float* __restrict__ x,
    const float* __restrict__ wq, const float* __restrict__ bq,
    const float* __restrict__ wk, const float* __restrict__ bk,
    const float* __restrict__ wv, const float* __restrict__ bv,
    _Float16* __restrict__ Qf, _Float16* __restrict__ Kf,
    _Float16* __restrict__ Vf)
{
    __shared__ float W[80][64];
    __shared__ float bias[80];
    __shared__ float qs[32][9];
    __shared__ float ks[32][9];
    __shared__ _Float16 vs[32][72];
    const int tid = threadIdx.x;
    for (int idx = tid; idx < 80 * 64; idx += 256) {
        int o = idx >> 6, c = idx & 63;
        float w;
        if (o < 8)       w = wq[o * 64 + c];
        else if (o < 16) w = wk[(o - 8) * 64 + c];
        else             w = wv[(o - 16) * 64 + c];
        W[o][c] = w;
    }
    if (tid < 80) {
        float bb;
        if (tid < 8)       bb = bq[tid];
        else if (tid < 16) bb = bk[tid - 8];
        else               bb = bv[tid - 16];
        bias[tid] = bb;
    }
    __syncthreads();

    const int js = blockIdx.x;          // 0..287
    const int b  = blockIdx.y;
    const int part = tid >> 5;          // 0..7
    const int jl   = tid & 31;
    const int i    = js * 32 + jl;

    float xr[64];
    #pragma unroll
    for (int c = 0; c < 64; ++c)
        xr[c] = x[(size_t)(b * 64 + c) * NPOS + i];

    #pragma unroll
    for (int q = 0; q < 10; ++q) {
        const int o = part * 10 + q;
        float s = bias[o];
        #pragma unroll
        for (int c4 = 0; c4 < 16; ++c4) {
            float4 w4 = *(const float4*)&W[o][c4 * 4];
            s += w4.x * xr[c4*4+0] + w4.y * xr[c4*4+1]
               + w4.z * xr[c4*4+2] + w4.w * xr[c4*4+3];
        }
        if (o < 8)       qs[jl][o] = s;
        else if (o < 16) ks[jl][o - 8] = s;
        else             vs[jl][o - 16] = (_Float16)s;
    }
    __syncthreads();

    const size_t tile = (size_t)b * NST + js;
    {   // Vf
        const int ct = tid >> 6, l = tid & 63;
        const int g = l >> 4, cl = l & 15;
        half8 o8;
        #pragma unroll
        for (int idx = 0; idx < 8; ++idx)
            o8[idx] = vs[8 * g + idx][16 * ct + cl];
        *(half8*)&Vf[(tile * 256 + ct * 64 + l) * 8] = o8;
    }
    if (tid < 128) {   // Qf (j-permuted, log2e-scaled)
        const int l = tid >> 1, e = tid & 1;
        const int m = l & 15, g = l >> 4;
        const int jsrc = 8 * (m >> 2) + 4 * e + (m & 3);
        constexpr float LOG2E = 1.44269504088896f;
        half4 qh;
        #pragma unroll
        for (int r = 0; r < 4; ++r)
            qh[r] = (g < 2) ? (_Float16)(qs[jsrc][4 * g + r] * LOG2E)
                            : (_Float16)0.f;
        ((half4*)Qf)[(tile * 64 + l) * 2 + e] = qh;
    } else {           // Kf (augment dims d=8,9 -> 1.0)
        const int t = tid - 128;
        const int ht = t >> 6, l = t & 63;
        const int il = l & 15, g = l >> 4;
        const int it = js * 2 + ht;
        half4 kh;
        #pragma unroll
        for (int r = 0; r < 4; ++r) {
            if (g < 2)       kh[r] = (_Float16)ks[16 * ht + il][4 * g + r];
            else if (g == 2) kh[r] = (r < 2) ? (_Float16)1.f : (_Float16)0.f;
            else             kh[r] = (_Float16)0.f;
        }
        ((half4*)Kf)[(size_t)(b * NT + it) * 64 + l] = kh;
    }
}

// ---------------------------------------------------------------------------
// K2: denom + patch fused. NOW 512 threads (8 waves) per block: each wave
// covers 36 tile-pairs instead of 72 -> 4.5 waves/SIMD for latency hiding.
// ---------------------------------------------------------------------------
__global__ __launch_bounds__(512, 4) void denom_kernel(
    _Float16* __restrict__ Qf, const _Float16* __restrict__ Kf)
{
    __shared__ float LpS[8][32];
    const int tid = threadIdx.x;
    const int w = tid >> 6, l = tid & 63;   // w = 0..7
    const int js = blockIdx.x;          // 0..287
    const int b  = blockIdx.y;
    const size_t tile = (size_t)b * NST + js;
    const half8* __restrict__ qfb = (const half8*)Qf + (size_t)b * NST * 64;
    const half4* __restrict__ kfb = (const half4*)Kf + (size_t)b * NT * 64;

    half8 qv = qfb[(size_t)js * 64 + l];
    half4 q0 = __builtin_shufflevector(qv, qv, 0, 1, 2, 3);
    half4 q1 = __builtin_shufflevector(qv, qv, 4, 5, 6, 7);

    float sum[2][4];
    #pragma unroll
    for (int e = 0; e < 2; ++e)
        #pragma unroll
        for (int r = 0; r < 4; ++r) sum[e][r] = 0.f;

    const floatx4 z = {0.f, 0.f, 0.f, 0.f};
    #define DACC(E0, E1) do { \
        _Pragma("unroll") \
        for (int r = 0; r < 4; ++r) { \
            sum[0][r] += EXP2(E0[r]); sum[1][r] += EXP2(E1[r]); } \
    } while (0)

    // wave w reads i-tiles w + 8m, m = 0..71 (stride 8 tiles = 512 half4)
    const half4* kp = kfb + (size_t)w * 64 + l;
    half4 kfA = kp[0];
    half4 kfB = kp[512];
    floatx4 eA0 = MFMA16(q0, kfA, z), eA1 = MFMA16(q1, kfA, z);
    floatx4 eB0, eB1;
    for (int k = 0; k < 35; ++k) {
        kfA = kp[(size_t)(2 * k + 2) * 512];
        eB0 = MFMA16(q0, kfB, z); eB1 = MFMA16(q1, kfB, z);
        DACC(eA0, eA1);
        kfB = kp[(size_t)(2 * k + 3) * 512];
        eA0 = MFMA16(q0, kfA, z); eA1 = MFMA16(q1, kfA, z);
        DACC(eB0, eB1);
    }
    eB0 = MFMA16(q0, kfB, z); eB1 = MFMA16(q1, kfB, z);
    DACC(eA0, eA1);
    DACC(eB0, eB1);
    #undef DACC

    #pragma unroll
    for (int e = 0; e < 2; ++e)
        #pragma unroll
        for (int r = 0; r < 4; ++r)
            #pragma unroll
            for (int m = 1; m < 16; m <<= 1)
                sum[e][r] += __shfl_xor(sum[e][r], m, 64);

    if ((l & 15) == 0) {
        const int g = l >> 4;
        #pragma unroll
        for (int e = 0; e < 2; ++e)
            #pragma unroll
            for (int r = 0; r < 4; ++r)
                LpS[w][8 * g + 4 * e + r] = sum[e][r];
    }
    __syncthreads();

    if (tid < 32) {
        float L = 0.f;
        #pragma unroll
        for (int u = 0; u < 8; ++u) L += LpS[u][tid];
        const float v = -__log2f(L);
        _Float16 hi = (_Float16)v;
        _Float16 lo = (_Float16)(v - (float)hi);
        const int m = 4 * (tid >> 3) + (tid & 3);
        const int e = (tid >> 2) & 1;
        half2v hl = {hi, lo};
        ((half2v*)Qf)[((tile * 64 + m + 32) * 2 + e) * 2] = hl;
    }
}

// ---------------------------------------------------------------------------
// K3: attention. NOW j-split x2: grid (384, 2); block = 48 i x HALF the j
// range (144 of 288 j-steps; each wave 36 steps of 32 j). Writes f32 partial
// sums to part[jh]; combine_kernel finishes out = gamma*(P0+P1) + x.
// 768 blocks = exactly 3 blocks/CU (LDS 3x51KB = 153KB), vs 1.5 before.
// ---------------------------------------------------------------------------
__global__ __launch_bounds__(256, 3) void attn_kernel(
    const _Float16* __restrict__ Qf, const _Float16* __restrict__ Kf,
    const _Float16* __restrict__ Vf,
    float* __restrict__ part)
{
    __shared__ float red[4][3][64][17];   // 52.2 KB
    const int s   = blockIdx.x;          // 0..383
    const int jh  = blockIdx.y;          // 0..1  (j-half)
    const int b   = s & 1;
    const int igl = s >> 1;              // 0..191
    const int tid = threadIdx.x;
    const int w = tid >> 6, l = tid & 63;
    const int it0 = igl * 3, i0 = igl * 48;

    const half8* __restrict__ qfb = (const half8*)Qf + (size_t)b * NST * 64;
    const half4* __restrict__ kfb = (const half4*)Kf + (size_t)b * NT * 64;
    const half8* __restrict__ vfb = (const half8*)Vf + (size_t)b * NST * 256;

    half4 kf[3];
    #pragma unroll
    for (int st = 0; st < 3; ++st) kf[st] = kfb[(size_t)(it0 + st) * 64 + l];

    floatx4 acc[3][4];
    #pragma unroll
    for (int st = 0; st < 3; ++st)
        #pragma unroll
        for (int ct = 0; ct < 4; ++ct)
            acc[st][ct] = (floatx4){0.f, 0.f, 0.f, 0.f};

    const floatx4 z = {0.f, 0.f, 0.f, 0.f};

    #define ASTEP(QV, V0, V1, V2, V3) do { \
        half4 qe0 = __builtin_shufflevector(QV, QV, 0, 1, 2, 3); \
        half4 qe1 = __builtin_shufflevector(QV, QV, 4, 5, 6, 7); \
        _Pragma("unroll") \
        for (int st = 0; st < 3; ++st) { \
            floatx4 e0 = MFMA16(qe0, kf[st], z); \
            floatx4 e1 = MFMA16(qe1, kf[st], z); \
            half8 p = p8_of(e0, e1); \
            acc[st][0] = MFMA32(V0, p, acc[st][0]); \
            acc[st][1] = MFMA32(V1, p, acc[st][1]); \
            acc[st][2] = MFMA32(V2, p, acc[st][2]); \
            acc[st][3] = MFMA32(V3, p, acc[st][3]); \
        } \
    } while (0)

    // wave w: j-steps st0 + w + 4k, k = 0..35 (st0 = jh*144)
    const int st0 = jh * (NST / 2);
    const half8* qpw = qfb + (size_t)(st0 + w) * 64 + l;
    const half8* vpw = vfb + (size_t)(st0 + w) * 256 + l;

    half8 qv = qpw[0];
    half8 v0 = vpw[0], v1 = vpw[64], v2 = vpw[128], v3 = vpw[192];
    for (int k = 0; k < 35; ++k) {
        const size_t nx = (size_t)(k + 1);
        half8 qn  = qpw[nx * 256];
        half8 v0n = vpw[nx * 1024],       v1n = vpw[nx * 1024 + 64];
        half8 v2n = vpw[nx * 1024 + 128], v3n = vpw[nx * 1024 + 192];
        ASTEP(qv, v0, v1, v2, v3);
        qv = qn; v0 = v0n; v1 = v1n; v2 = v2n; v3 = v3n;
    }
    ASTEP(qv, v0, v1, v2, v3);
    #undef ASTEP

    #pragma unroll
    for (int st = 0; st < 3; ++st)
        #pragma unroll
        for (int ct = 0; ct < 4; ++ct)
            #pragma unroll
            for (int r = 0; r < 4; ++r)
                red[w][st][l][ct * 4 + r] = acc[st][ct][r];
    __syncthreads();

    if (w < 3) {
        float* __restrict__ P =
            part + (size_t)jh * ((size_t)BATCH * 64 * NPOS);
        const int iq = i0 + 16 * w + (l & 15);
        #pragma unroll
        for (int ct = 0; ct < 4; ++ct)
            #pragma unroll
            for (int r = 0; r < 4; ++r) {
                float v = red[0][w][l][ct*4+r] + red[1][w][l][ct*4+r]
                        + red[2][w][l][ct*4+r] + red[3][w][l][ct*4+r];
                int c = 16 * ct + 4 * (l >> 4) + r;
                size_t o = ((size_t)(b * 64 + c)) * NPOS + iq;
                P[o] = v;
            }
    }
}

// ---------------------------------------------------------------------------
// K4: combine epilogue — out = gamma * (P0 + P1) + x.  ~19 MB traffic.
// ---------------------------------------------------------------------------
__global__ __launch_bounds__(256) void combine_kernel(
    const float* __restrict__ part, const float* __restrict__ x,
    const float* __restrict__ gamma, float* __restrict__ out)
{
    const float g = gamma[0];
    const size_t idx = (size_t)blockIdx.x * 256 + threadIdx.x; // 0..294911
    const float4* p0 = (const float4*)part;
    const float4* p1 = p0 + ((size_t)BATCH * 64 * NPOS) / 4;
    float4 a  = p0[idx];
    float4 c  = p1[idx];
    float4 xv = ((const float4*)x)[idx];
    float4 o;
    o.x = g * (a.x + c.x) + xv.x;
    o.y = g * (a.y + c.y) + xv.y;
    o.z = g * (a.z + c.z) + xv.z;
    o.w = g * (a.w + c.w) + xv.w;
    ((float4*)out)[idx] = o;
}

// ---------------------------------------------------------------------------
extern "C" void kernel_launch(void* const* d_in, const int* in_sizes, int n_in,
                              void* d_out, int out_size, void* d_ws, size_t ws_size,
                              hipStream_t stream)
{
    const float* x     = (const float*)d_in[0];
    const float* wq    = (const float*)d_in[1];
    const float* bq    = (const float*)d_in[2];
    const float* wk    = (const float*)d_in[3];
    const float* bk    = (const float*)d_in[4];
    const float* wv    = (const float*)d_in[5];
    const float* bv    = (const float*)d_in[6];
    const float* gamma = (const float*)d_in[7];
    float* out = (float*)d_out;

    char* wsb = (char*)d_ws;
    _Float16* Qf = (_Float16*)wsb;                       //   589,824 B
    _Float16* Kf = (_Float16*)(wsb + 589824);            //   589,824 B
    _Float16* Vf = (_Float16*)(wsb + 1179648);           // 2,359,296 B
    float*    Pp = (float*)(wsb + 3538944);              // 2 x 4,718,592 B

    qkv_kernel<<<dim3(NST, BATCH), 256, 0, stream>>>(
        x, wq, bq, wk, bk, wv, bv, Qf, Kf, Vf);

    denom_kernel<<<dim3(NST, BATCH), 512, 0, stream>>>(Qf, Kf);

    attn_kernel<<<dim3(384, 2), 256, 0, stream>>>(Qf, Kf, Vf, Pp);

    combine_kernel<<<(BATCH * 64 * NPOS / 4) / 256, 256, 0, stream>>>(
        Pp, x, gamma, out);
}